// Round 1
// baseline (284.008 us; speedup 1.0000x reference)
//
#include <hip/hip_runtime.h>
#include <hip/hip_bf16.h>

#define D_SRC 256
#define D_REL 128

// ---------------- zero scratch ----------------
__global__ void zero_kernel(int* __restrict__ p, int n) {
    int i = blockIdx.x * 256 + threadIdx.x;
    if (i < n) p[i] = 0;
}

// ---------------- projection: p_src = x_src @ W_src ----------------
// Block: 256 threads, tile 64 rows x 128 cols, K-tile 32, per-thread 8x4.
__global__ __launch_bounds__(256) void proj_kernel(
    const float* __restrict__ x, const float* __restrict__ W,
    float* __restrict__ out, int M) {
    __shared__ float xs[32][64];     // transposed x tile: xs[k][row]
    __shared__ float ws_[32][128];   // W tile: ws_[k][col]

    int tid = threadIdx.x;
    int row0 = blockIdx.x * 64;
    int tx = tid & 31;   // col group: cols tx*4 .. tx*4+3
    int ty = tid >> 5;   // row group: rows ty*8 .. ty*8+7

    float acc[8][4];
#pragma unroll
    for (int r = 0; r < 8; ++r)
#pragma unroll
        for (int c = 0; c < 4; ++c) acc[r][c] = 0.f;

    for (int kt = 0; kt < D_SRC; kt += 32) {
        // load x tile (64 rows x 32 k) transposed into xs
        {
            int i = tid;
#pragma unroll
            for (int rep = 0; rep < 2; ++rep, i += 256) {
                int r = i >> 3;          // 0..63
                int c4 = i & 7;          // float4 index in 32 cols
                int row = row0 + r;
                float4 v = make_float4(0.f, 0.f, 0.f, 0.f);
                if (row < M)
                    v = *(const float4*)(x + (size_t)row * D_SRC + kt + c4 * 4);
                xs[c4 * 4 + 0][r] = v.x;
                xs[c4 * 4 + 1][r] = v.y;
                xs[c4 * 4 + 2][r] = v.z;
                xs[c4 * 4 + 3][r] = v.w;
            }
        }
        // load W tile (32 k x 128 cols)
        {
#pragma unroll
            for (int rep = 0; rep < 4; ++rep) {
                int i = tid + rep * 256;  // 0..1023
                int k = i >> 5;           // 0..31
                int c4 = i & 31;          // float4 col
                *(float4*)&ws_[k][c4 * 4] =
                    *(const float4*)(W + (size_t)(kt + k) * D_REL + c4 * 4);
            }
        }
        __syncthreads();

#pragma unroll
        for (int k = 0; k < 32; ++k) {
            float xv[8], wv[4];
            *(float4*)&xv[0] = *(float4*)&xs[k][ty * 8];
            *(float4*)&xv[4] = *(float4*)&xs[k][ty * 8 + 4];
            *(float4*)&wv[0] = *(float4*)&ws_[k][tx * 4];
#pragma unroll
            for (int r = 0; r < 8; ++r)
#pragma unroll
                for (int c = 0; c < 4; ++c) acc[r][c] += xv[r] * wv[c];
        }
        __syncthreads();
    }

#pragma unroll
    for (int r = 0; r < 8; ++r) {
        int row = row0 + ty * 8 + r;
        if (row < M)
            *(float4*)(out + (size_t)row * D_REL + tx * 4) = *(float4*)&acc[r][0];
    }
}

// ---------------- degree count ----------------
__global__ void count_kernel(const int* __restrict__ edge_dst, int* __restrict__ deg_i, int E) {
    int e = blockIdx.x * 256 + threadIdx.x;
    if (e < E) atomicAdd(&deg_i[edge_dst[e]], 1);
}

// ---------------- 2-level exclusive scan ----------------
__global__ __launch_bounds__(1024) void scan_blocks(
    const int* __restrict__ deg_i, int* __restrict__ incl,
    int* __restrict__ bsums, int n) {
    int i = blockIdx.x * 1024 + threadIdx.x;
    int v = (i < n) ? deg_i[i] : 0;
    int lane = threadIdx.x & 63;
    int wid = threadIdx.x >> 6;
    int x = v;
#pragma unroll
    for (int off = 1; off < 64; off <<= 1) {
        int y = __shfl_up(x, off, 64);
        if (lane >= off) x += y;
    }
    __shared__ int wsum[16];
    if (lane == 63) wsum[wid] = x;
    __syncthreads();
    if (wid == 0 && lane < 16) {
        int s = wsum[lane];
#pragma unroll
        for (int off = 1; off < 16; off <<= 1) {
            int y = __shfl_up(s, off, 64);
            if (lane >= off) s += y;
        }
        wsum[lane] = s;
    }
    __syncthreads();
    int add = (wid > 0) ? wsum[wid - 1] : 0;
    x += add;
    if (i < n) incl[i] = x;
    if (threadIdx.x == 1023) bsums[blockIdx.x] = x;
}

__global__ __launch_bounds__(128) void scan_sums(int* __restrict__ bs, int nb) {
    __shared__ int tmp[128];
    int t = threadIdx.x;
    int v = (t < nb) ? bs[t] : 0;
    tmp[t] = v;
    __syncthreads();
    for (int off = 1; off < 128; off <<= 1) {
        int y = 0;
        if (t >= off) y = tmp[t - off];
        __syncthreads();
        tmp[t] += y;
        __syncthreads();
    }
    if (t < nb) bs[t] = tmp[t] - v;  // exclusive
}

__global__ __launch_bounds__(1024) void finalize_kernel(
    const int* __restrict__ deg_i, const int* __restrict__ incl,
    const int* __restrict__ bsums, int* __restrict__ row_start,
    float* __restrict__ deg_out, int n, int E) {
    int i = blockIdx.x * 1024 + threadIdx.x;
    if (i < n) {
        int off = bsums[blockIdx.x];
        row_start[i] = off + incl[i] - deg_i[i];
        deg_out[i] = (float)max(deg_i[i], 1);
    }
    if (i == 0) row_start[n] = E;
}

// ---------------- bucket fill ----------------
__global__ void fill_kernel(const int* __restrict__ edge_src,
                            const int* __restrict__ edge_dst,
                            const int* __restrict__ row_start,
                            int* __restrict__ cursor,
                            int* __restrict__ bucket, int E) {
    int e = blockIdx.x * 256 + threadIdx.x;
    if (e < E) {
        int d = edge_dst[e];
        int pos = atomicAdd(&cursor[d], 1);
        bucket[row_start[d] + pos] = edge_src[e];
    }
}

// ---------------- gather: one wave per dst row ----------------
__global__ __launch_bounds__(256) void gather_kernel(
    const float* __restrict__ p_src, const int* __restrict__ row_start,
    const int* __restrict__ bucket, const float* __restrict__ deg_out,
    float* __restrict__ dst, int n) {
    int row = blockIdx.x * 4 + (threadIdx.x >> 6);
    int lane = threadIdx.x & 63;
    if (row >= n) return;
    int beg = row_start[row], end = row_start[row + 1];
    const float2* p2 = (const float2*)p_src;
    float2 acc = make_float2(0.f, 0.f);
    for (int idx = beg; idx < end; ++idx) {
        int s = bucket[idx];
        float2 v = p2[(size_t)s * 64 + lane];
        acc.x += v.x;
        acc.y += v.y;
    }
    float dinv = 1.0f / deg_out[row];
    float2 o;
    o.x = acc.x * dinv;
    o.y = acc.y * dinv;
    ((float2*)dst)[(size_t)row * 64 + lane] = o;
}

extern "C" void kernel_launch(void* const* d_in, const int* in_sizes, int n_in,
                              void* d_out, int out_size, void* d_ws, size_t ws_size,
                              hipStream_t stream) {
    const float* x_src = (const float*)d_in[0];
    const float* W_src = (const float*)d_in[2];
    const int* edge_src = (const int*)d_in[4];
    const int* edge_dst = (const int*)d_in[5];

    const int N_SRC = in_sizes[0] / D_SRC;
    const int N_DST = in_sizes[1] / D_SRC;
    const int E = in_sizes[4];

    float* out_dst = (float*)d_out;                          // [N_DST, 128]
    float* out_psrc = out_dst + (size_t)N_DST * D_REL;       // [N_SRC, 128]
    float* out_deg = out_psrc + (size_t)N_SRC * D_REL;       // [N_DST]

    int* deg_i = (int*)d_ws;               // N_DST
    int* cursor = deg_i + N_DST;           // N_DST
    int* incl = cursor + N_DST;            // N_DST
    int* row_start = incl + N_DST;         // N_DST+1
    int* bsums = row_start + N_DST + 1;    // 128
    int* bucket = bsums + 128;             // E

    // 1. zero deg_i + cursor (adjacent)
    {
        int n2 = 2 * N_DST;
        zero_kernel<<<(n2 + 255) / 256, 256, 0, stream>>>(deg_i, n2);
    }
    // 2. projection
    proj_kernel<<<(N_SRC + 63) / 64, 256, 0, stream>>>(x_src, W_src, out_psrc, N_SRC);
    // 3. degree count
    count_kernel<<<(E + 255) / 256, 256, 0, stream>>>(edge_dst, deg_i, E);
    // 4. scan
    int nb = (N_DST + 1023) / 1024;
    scan_blocks<<<nb, 1024, 0, stream>>>(deg_i, incl, bsums, N_DST);
    scan_sums<<<1, 128, 0, stream>>>(bsums, nb);
    finalize_kernel<<<nb, 1024, 0, stream>>>(deg_i, incl, bsums, row_start, out_deg, N_DST, E);
    // 5. bucket fill
    fill_kernel<<<(E + 255) / 256, 256, 0, stream>>>(edge_src, edge_dst, row_start, cursor, bucket, E);
    // 6. gather + normalize
    gather_kernel<<<(N_DST + 3) / 4, 256, 0, stream>>>(out_psrc, row_start, bucket, out_deg, out_dst, N_DST);
}

// Round 2
// 219.723 us; speedup vs baseline: 1.2926x; 1.2926x over previous
//
#include <hip/hip_runtime.h>
#include <hip/hip_bf16.h>

#define D_SRC 256
#define D_REL 128

typedef __bf16 bf16x8 __attribute__((ext_vector_type(8)));
typedef float f32x4 __attribute__((ext_vector_type(4)));

// ---------------- zero scratch ----------------
__global__ void zero_kernel(int* __restrict__ p, int n) {
    int i = blockIdx.x * 256 + threadIdx.x;
    if (i < n) p[i] = 0;
}

// ---------------- prep: arrange W (fp32 [256][128]) into MFMA B-fragment order ----------------
// Wt[(kstep*8+n)*64 + lane] = bf16x8 { W[kstep*32 + (lane>>4)*8 + j][n*16 + (lane&15)] , j=0..7 }
__global__ __launch_bounds__(64) void prep_w_kernel(const float* __restrict__ W,
                                                    bf16x8* __restrict__ Wt) {
    int c = blockIdx.x;            // 0..63 = kstep*8 + n
    int ks = c >> 3, n = c & 7;
    int lane = threadIdx.x;
    int col = n * 16 + (lane & 15);
    int k0 = ks * 32 + (lane >> 4) * 8;
    bf16x8 v;
#pragma unroll
    for (int j = 0; j < 8; ++j) v[j] = (__bf16)W[(size_t)(k0 + j) * D_REL + col];
    Wt[c * 64 + lane] = v;
}

// ---------------- projection via bf16 MFMA: p_src = x_src @ W_src ----------------
// 512 threads = 8 waves; each wave computes 16 rows x 128 cols.
// B fragments staged once in LDS in fragment order (conflict-free lane*16 reads).
__global__ __launch_bounds__(512) void proj_mfma_kernel(
    const float* __restrict__ x, const f32x4* __restrict__ Wt,
    float* __restrict__ out, int M) {
    __shared__ f32x4 blds[4096];   // 64 KB, viewed as bf16x8[4096]
    int tid = threadIdx.x;
    // stage Wt -> LDS linearly (coalesced, conflict-free)
#pragma unroll
    for (int i = 0; i < 8; ++i) blds[tid + i * 512] = Wt[tid + i * 512];

    int wave = tid >> 6, lane = tid & 63;
    int row = blockIdx.x * 128 + wave * 16 + (lane & 15);
    int rowc = min(row, M - 1);
    int kb = lane >> 4;

    f32x4 acc[8];
#pragma unroll
    for (int n = 0; n < 8; ++n) acc[n] = (f32x4)(0.f);

    __syncthreads();

    const float* xr = x + (size_t)rowc * D_SRC + kb * 8;
    const bf16x8* b8 = (const bf16x8*)blds;
#pragma unroll
    for (int ks = 0; ks < 8; ++ks) {
        f32x4 a0 = *(const f32x4*)(xr + ks * 32);
        f32x4 a1 = *(const f32x4*)(xr + ks * 32 + 4);
        bf16x8 af;
        af[0] = (__bf16)a0[0]; af[1] = (__bf16)a0[1];
        af[2] = (__bf16)a0[2]; af[3] = (__bf16)a0[3];
        af[4] = (__bf16)a1[0]; af[5] = (__bf16)a1[1];
        af[6] = (__bf16)a1[2]; af[7] = (__bf16)a1[3];
#pragma unroll
        for (int n = 0; n < 8; ++n) {
            bf16x8 bf = b8[ks * 512 + n * 64 + lane];
            acc[n] = __builtin_amdgcn_mfma_f32_16x16x32_bf16(af, bf, acc[n], 0, 0, 0);
        }
    }

    // store: row = base + (lane>>4)*4 + reg, col = n*16 + (lane&15)
    int orow0 = blockIdx.x * 128 + wave * 16 + (lane >> 4) * 4;
    int ocol = lane & 15;
#pragma unroll
    for (int reg = 0; reg < 4; ++reg) {
        int r = orow0 + reg;
        if (r < M) {
            float* o = out + (size_t)r * D_REL + ocol;
#pragma unroll
            for (int n = 0; n < 8; ++n) o[n * 16] = acc[n][reg];
        }
    }
}

// ---------------- degree count ----------------
__global__ void count_kernel(const int* __restrict__ edge_dst, int* __restrict__ deg_i, int E) {
    int e = blockIdx.x * 256 + threadIdx.x;
    if (e < E) atomicAdd(&deg_i[edge_dst[e]], 1);
}

// ---------------- 2-level exclusive scan ----------------
__global__ __launch_bounds__(1024) void scan_blocks(
    const int* __restrict__ deg_i, int* __restrict__ incl,
    int* __restrict__ bsums, int n) {
    int i = blockIdx.x * 1024 + threadIdx.x;
    int v = (i < n) ? deg_i[i] : 0;
    int lane = threadIdx.x & 63;
    int wid = threadIdx.x >> 6;
    int x = v;
#pragma unroll
    for (int off = 1; off < 64; off <<= 1) {
        int y = __shfl_up(x, off, 64);
        if (lane >= off) x += y;
    }
    __shared__ int wsum[16];
    if (lane == 63) wsum[wid] = x;
    __syncthreads();
    if (wid == 0 && lane < 16) {
        int s = wsum[lane];
#pragma unroll
        for (int off = 1; off < 16; off <<= 1) {
            int y = __shfl_up(s, off, 64);
            if (lane >= off) s += y;
        }
        wsum[lane] = s;
    }
    __syncthreads();
    int add = (wid > 0) ? wsum[wid - 1] : 0;
    x += add;
    if (i < n) incl[i] = x;
    if (threadIdx.x == 1023) bsums[blockIdx.x] = x;
}

__global__ __launch_bounds__(128) void scan_sums(int* __restrict__ bs, int nb) {
    __shared__ int tmp[128];
    int t = threadIdx.x;
    int v = (t < nb) ? bs[t] : 0;
    tmp[t] = v;
    __syncthreads();
    for (int off = 1; off < 128; off <<= 1) {
        int y = 0;
        if (t >= off) y = tmp[t - off];
        __syncthreads();
        tmp[t] += y;
        __syncthreads();
    }
    if (t < nb) bs[t] = tmp[t] - v;  // exclusive
}

__global__ __launch_bounds__(1024) void finalize_kernel(
    const int* __restrict__ deg_i, const int* __restrict__ incl,
    const int* __restrict__ bsums, int* __restrict__ row_start,
    float* __restrict__ deg_out, int n, int E) {
    int i = blockIdx.x * 1024 + threadIdx.x;
    if (i < n) {
        int off = bsums[blockIdx.x];
        row_start[i] = off + incl[i] - deg_i[i];
        deg_out[i] = (float)max(deg_i[i], 1);
    }
    if (i == 0) row_start[n] = E;
}

// ---------------- bucket fill ----------------
__global__ void fill_kernel(const int* __restrict__ edge_src,
                            const int* __restrict__ edge_dst,
                            const int* __restrict__ row_start,
                            int* __restrict__ cursor,
                            int* __restrict__ bucket, int E) {
    int e = blockIdx.x * 256 + threadIdx.x;
    if (e < E) {
        int d = edge_dst[e];
        int pos = atomicAdd(&cursor[d], 1);
        bucket[row_start[d] + pos] = edge_src[e];
    }
}

// ---------------- gather: one wave per dst row ----------------
__global__ __launch_bounds__(256) void gather_kernel(
    const float* __restrict__ p_src, const int* __restrict__ row_start,
    const int* __restrict__ bucket, const float* __restrict__ deg_out,
    float* __restrict__ dst, int n) {
    int row = blockIdx.x * 4 + (threadIdx.x >> 6);
    int lane = threadIdx.x & 63;
    if (row >= n) return;
    int beg = row_start[row], end = row_start[row + 1];
    const float2* p2 = (const float2*)p_src;
    float2 acc = make_float2(0.f, 0.f);
    for (int idx = beg; idx < end; ++idx) {
        int s = bucket[idx];
        float2 v = p2[(size_t)s * 64 + lane];
        acc.x += v.x;
        acc.y += v.y;
    }
    float dinv = 1.0f / deg_out[row];
    float2 o;
    o.x = acc.x * dinv;
    o.y = acc.y * dinv;
    ((float2*)dst)[(size_t)row * 64 + lane] = o;
}

extern "C" void kernel_launch(void* const* d_in, const int* in_sizes, int n_in,
                              void* d_out, int out_size, void* d_ws, size_t ws_size,
                              hipStream_t stream) {
    const float* x_src = (const float*)d_in[0];
    const float* W_src = (const float*)d_in[2];
    const int* edge_src = (const int*)d_in[4];
    const int* edge_dst = (const int*)d_in[5];

    const int N_SRC = in_sizes[0] / D_SRC;
    const int N_DST = in_sizes[1] / D_SRC;
    const int E = in_sizes[4];

    float* out_dst = (float*)d_out;                          // [N_DST, 128]
    float* out_psrc = out_dst + (size_t)N_DST * D_REL;       // [N_SRC, 128]
    float* out_deg = out_psrc + (size_t)N_SRC * D_REL;       // [N_DST]

    int* deg_i = (int*)d_ws;               // N_DST
    int* cursor = deg_i + N_DST;           // N_DST
    int* incl = cursor + N_DST;            // N_DST
    int* row_start = incl + N_DST;         // N_DST+1
    int* bsums = row_start + N_DST + 1;    // 128
    int* bucket = bsums + 128;             // E
    // Wt (bf16 fragment-ordered W) after bucket, 256-byte aligned
    size_t int_bytes = (size_t)(4 * N_DST + 1 + 128 + E) * sizeof(int);
    size_t wt_off = (int_bytes + 255) & ~(size_t)255;
    bf16x8* Wt = (bf16x8*)((char*)d_ws + wt_off);   // 64 KB

    // 1. zero deg_i + cursor (adjacent)
    {
        int n2 = 2 * N_DST;
        zero_kernel<<<(n2 + 255) / 256, 256, 0, stream>>>(deg_i, n2);
    }
    // 2a. arrange W fragments
    prep_w_kernel<<<64, 64, 0, stream>>>(W_src, Wt);
    // 2b. projection (bf16 MFMA)
    proj_mfma_kernel<<<(N_SRC + 127) / 128, 512, 0, stream>>>(
        x_src, (const f32x4*)Wt, out_psrc, N_SRC);
    // 3. degree count
    count_kernel<<<(E + 255) / 256, 256, 0, stream>>>(edge_dst, deg_i, E);
    // 4. scan
    int nb = (N_DST + 1023) / 1024;
    scan_blocks<<<nb, 1024, 0, stream>>>(deg_i, incl, bsums, N_DST);
    scan_sums<<<1, 128, 0, stream>>>(bsums, nb);
    finalize_kernel<<<nb, 1024, 0, stream>>>(deg_i, incl, bsums, row_start, out_deg, N_DST, E);
    // 5. bucket fill
    fill_kernel<<<(E + 255) / 256, 256, 0, stream>>>(edge_src, edge_dst, row_start, cursor, bucket, E);
    // 6. gather + normalize
    gather_kernel<<<(N_DST + 3) / 4, 256, 0, stream>>>(out_psrc, row_start, bucket, out_deg, out_dst, N_DST);
}

// Round 3
// 146.934 us; speedup vs baseline: 1.9329x; 1.4954x over previous
//
#include <hip/hip_runtime.h>
#include <hip/hip_bf16.h>

#define D_SRC 256
#define D_REL 128

typedef __bf16 bf16x8 __attribute__((ext_vector_type(8)));
typedef float f32x4 __attribute__((ext_vector_type(4)));

// ---------------- zero scratch ----------------
__global__ void zero_kernel(int* __restrict__ p, int n) {
    int i = blockIdx.x * 256 + threadIdx.x;
    if (i < n) p[i] = 0;
}

// ---------------- prep: arrange W (fp32 [256][128]) into MFMA B-fragment order ----------------
__global__ __launch_bounds__(64) void prep_w_kernel(const float* __restrict__ W,
                                                    bf16x8* __restrict__ Wt) {
    int c = blockIdx.x;            // 0..63 = kstep*8 + n
    int ks = c >> 3, n = c & 7;
    int lane = threadIdx.x;
    int col = n * 16 + (lane & 15);
    int k0 = ks * 32 + (lane >> 4) * 8;
    bf16x8 v;
#pragma unroll
    for (int j = 0; j < 8; ++j) v[j] = (__bf16)W[(size_t)(k0 + j) * D_REL + col];
    Wt[c * 64 + lane] = v;
}

// ---------------- projection via bf16 MFMA: p_src = x_src @ W_src ----------------
// Also writes a bf16 copy of p_src for the gather stage.
__global__ __launch_bounds__(512) void proj_mfma_kernel(
    const float* __restrict__ x, const f32x4* __restrict__ Wt,
    float* __restrict__ out, unsigned short* __restrict__ out_bf, int M) {
    __shared__ f32x4 blds[4096];   // 64 KB
    int tid = threadIdx.x;
#pragma unroll
    for (int i = 0; i < 8; ++i) blds[tid + i * 512] = Wt[tid + i * 512];

    int wave = tid >> 6, lane = tid & 63;
    int row = blockIdx.x * 128 + wave * 16 + (lane & 15);
    int rowc = min(row, M - 1);
    int kb = lane >> 4;

    f32x4 acc[8];
#pragma unroll
    for (int n = 0; n < 8; ++n) acc[n] = (f32x4)(0.f);

    __syncthreads();

    const float* xr = x + (size_t)rowc * D_SRC + kb * 8;
    const bf16x8* b8 = (const bf16x8*)blds;
#pragma unroll
    for (int ks = 0; ks < 8; ++ks) {
        f32x4 a0 = *(const f32x4*)(xr + ks * 32);
        f32x4 a1 = *(const f32x4*)(xr + ks * 32 + 4);
        bf16x8 af;
        af[0] = (__bf16)a0[0]; af[1] = (__bf16)a0[1];
        af[2] = (__bf16)a0[2]; af[3] = (__bf16)a0[3];
        af[4] = (__bf16)a1[0]; af[5] = (__bf16)a1[1];
        af[6] = (__bf16)a1[2]; af[7] = (__bf16)a1[3];
#pragma unroll
        for (int n = 0; n < 8; ++n) {
            bf16x8 bf = b8[ks * 512 + n * 64 + lane];
            acc[n] = __builtin_amdgcn_mfma_f32_16x16x32_bf16(af, bf, acc[n], 0, 0, 0);
        }
    }

    // store: row = base + (lane>>4)*4 + reg, col = n*16 + (lane&15)
    int orow0 = blockIdx.x * 128 + wave * 16 + (lane >> 4) * 4;
    int ocol = lane & 15;
#pragma unroll
    for (int reg = 0; reg < 4; ++reg) {
        int r = orow0 + reg;
        if (r < M) {
            float* o = out + (size_t)r * D_REL + ocol;
            unsigned short* ob = out_bf + (size_t)r * D_REL + ocol;
#pragma unroll
            for (int n = 0; n < 8; ++n) {
                float v = acc[n][reg];
                o[n * 16] = v;
                ob[n * 16] = (unsigned short)(__bfloat16_as_ushort(__float2bfloat16(v)));
            }
        }
    }
}

// ---------------- degree count + per-edge bucket position ----------------
__global__ void count_kernel(const int* __restrict__ edge_dst, int* __restrict__ deg_i,
                             int* __restrict__ pos_arr, int E) {
    int e = blockIdx.x * 256 + threadIdx.x;
    if (e < E) pos_arr[e] = atomicAdd(&deg_i[edge_dst[e]], 1);
}

// ---------------- 2-level exclusive scan ----------------
__global__ __launch_bounds__(1024) void scan_blocks(
    const int* __restrict__ deg_i, int* __restrict__ incl,
    int* __restrict__ bsums, int n) {
    int i = blockIdx.x * 1024 + threadIdx.x;
    int v = (i < n) ? deg_i[i] : 0;
    int lane = threadIdx.x & 63;
    int wid = threadIdx.x >> 6;
    int x = v;
#pragma unroll
    for (int off = 1; off < 64; off <<= 1) {
        int y = __shfl_up(x, off, 64);
        if (lane >= off) x += y;
    }
    __shared__ int wsum[16];
    if (lane == 63) wsum[wid] = x;
    __syncthreads();
    if (wid == 0 && lane < 16) {
        int s = wsum[lane];
#pragma unroll
        for (int off = 1; off < 16; off <<= 1) {
            int y = __shfl_up(s, off, 64);
            if (lane >= off) s += y;
        }
        wsum[lane] = s;
    }
    __syncthreads();
    int add = (wid > 0) ? wsum[wid - 1] : 0;
    x += add;
    if (i < n) incl[i] = x;
    if (threadIdx.x == 1023) bsums[blockIdx.x] = x;
}

__global__ __launch_bounds__(128) void scan_sums(int* __restrict__ bs, int nb) {
    __shared__ int tmp[128];
    int t = threadIdx.x;
    int v = (t < nb) ? bs[t] : 0;
    tmp[t] = v;
    __syncthreads();
    for (int off = 1; off < 128; off <<= 1) {
        int y = 0;
        if (t >= off) y = tmp[t - off];
        __syncthreads();
        tmp[t] += y;
        __syncthreads();
    }
    if (t < nb) bs[t] = tmp[t] - v;  // exclusive
}

__global__ __launch_bounds__(1024) void finalize_kernel(
    const int* __restrict__ deg_i, const int* __restrict__ incl,
    const int* __restrict__ bsums, int* __restrict__ row_start,
    float* __restrict__ deg_out, int n, int E) {
    int i = blockIdx.x * 1024 + threadIdx.x;
    if (i < n) {
        int off = bsums[blockIdx.x];
        row_start[i] = off + incl[i] - deg_i[i];
        deg_out[i] = (float)max(deg_i[i], 1);
    }
    if (i == 0) row_start[n] = E;
}

// ---------------- bucket fill (atomic-free) ----------------
__global__ void fill_kernel(const int* __restrict__ edge_src,
                            const int* __restrict__ edge_dst,
                            const int* __restrict__ row_start,
                            const int* __restrict__ pos_arr,
                            int* __restrict__ bucket, int E) {
    int e = blockIdx.x * 256 + threadIdx.x;
    if (e < E) {
        int d = edge_dst[e];
        bucket[row_start[d] + pos_arr[e]] = edge_src[e];
    }
}

// ---------------- gather: one wave per dst row, bf16 source, 4-deep pipeline ----------------
__global__ __launch_bounds__(256) void gather_kernel(
    const unsigned int* __restrict__ p_bf, const int* __restrict__ row_start,
    const int* __restrict__ bucket, const float* __restrict__ deg_out,
    float* __restrict__ dst, int n) {
    int row = blockIdx.x * 4 + (threadIdx.x >> 6);
    int lane = threadIdx.x & 63;
    if (row >= n) return;
    int beg = row_start[row], end = row_start[row + 1];
    float ax = 0.f, ay = 0.f;
    int idx = beg;
    for (; idx + 4 <= end; idx += 4) {
        int s0 = bucket[idx + 0];
        int s1 = bucket[idx + 1];
        int s2 = bucket[idx + 2];
        int s3 = bucket[idx + 3];
        unsigned int v0 = p_bf[(size_t)s0 * 64 + lane];
        unsigned int v1 = p_bf[(size_t)s1 * 64 + lane];
        unsigned int v2 = p_bf[(size_t)s2 * 64 + lane];
        unsigned int v3 = p_bf[(size_t)s3 * 64 + lane];
        ax += __uint_as_float(v0 << 16) + __uint_as_float(v1 << 16)
            + __uint_as_float(v2 << 16) + __uint_as_float(v3 << 16);
        ay += __uint_as_float(v0 & 0xffff0000u) + __uint_as_float(v1 & 0xffff0000u)
            + __uint_as_float(v2 & 0xffff0000u) + __uint_as_float(v3 & 0xffff0000u);
    }
    for (; idx < end; ++idx) {
        int s = bucket[idx];
        unsigned int v = p_bf[(size_t)s * 64 + lane];
        ax += __uint_as_float(v << 16);
        ay += __uint_as_float(v & 0xffff0000u);
    }
    float dinv = 1.0f / deg_out[row];
    float2 o;
    o.x = ax * dinv;
    o.y = ay * dinv;
    ((float2*)dst)[(size_t)row * 64 + lane] = o;
}

extern "C" void kernel_launch(void* const* d_in, const int* in_sizes, int n_in,
                              void* d_out, int out_size, void* d_ws, size_t ws_size,
                              hipStream_t stream) {
    const float* x_src = (const float*)d_in[0];
    const float* W_src = (const float*)d_in[2];
    const int* edge_src = (const int*)d_in[4];
    const int* edge_dst = (const int*)d_in[5];

    const int N_SRC = in_sizes[0] / D_SRC;
    const int N_DST = in_sizes[1] / D_SRC;
    const int E = in_sizes[4];

    float* out_dst = (float*)d_out;                          // [N_DST, 128]
    float* out_psrc = out_dst + (size_t)N_DST * D_REL;       // [N_SRC, 128]
    float* out_deg = out_psrc + (size_t)N_SRC * D_REL;       // [N_DST]

    int* deg_i = (int*)d_ws;               // N_DST
    int* incl = deg_i + N_DST;             // N_DST
    int* row_start = incl + N_DST;         // N_DST+1
    int* bsums = row_start + N_DST + 1;    // 128
    int* pos_arr = bsums + 128;            // E
    int* bucket = pos_arr + E;             // E
    size_t int_bytes = (size_t)(3 * N_DST + 1 + 128 + 2 * (size_t)E) * sizeof(int);
    size_t wt_off = (int_bytes + 255) & ~(size_t)255;
    bf16x8* Wt = (bf16x8*)((char*)d_ws + wt_off);            // 64 KB
    size_t pbf_off = wt_off + 65536;
    unsigned short* p_bf = (unsigned short*)((char*)d_ws + pbf_off);  // N_SRC*128 bf16

    // 1. zero deg_i
    zero_kernel<<<(N_DST + 255) / 256, 256, 0, stream>>>(deg_i, N_DST);
    // 2a. arrange W fragments
    prep_w_kernel<<<64, 64, 0, stream>>>(W_src, Wt);
    // 2b. projection (bf16 MFMA) + bf16 copy
    proj_mfma_kernel<<<(N_SRC + 127) / 128, 512, 0, stream>>>(
        x_src, (const f32x4*)Wt, out_psrc, p_bf, N_SRC);
    // 3. degree count + per-edge position
    count_kernel<<<(E + 255) / 256, 256, 0, stream>>>(edge_dst, deg_i, pos_arr, E);
    // 4. scan
    int nb = (N_DST + 1023) / 1024;
    scan_blocks<<<nb, 1024, 0, stream>>>(deg_i, incl, bsums, N_DST);
    scan_sums<<<1, 128, 0, stream>>>(bsums, nb);
    finalize_kernel<<<nb, 1024, 0, stream>>>(deg_i, incl, bsums, row_start, out_deg, N_DST, E);
    // 5. bucket fill (atomic-free)
    fill_kernel<<<(E + 255) / 256, 256, 0, stream>>>(edge_src, edge_dst, row_start, pos_arr, bucket, E);
    // 6. gather + normalize (bf16 source)
    gather_kernel<<<(N_DST + 3) / 4, 256, 0, stream>>>(
        (const unsigned int*)p_bf, row_start, bucket, out_deg, out_dst, N_DST);
}